// Round 1
// 370.274 us; speedup vs baseline: 1.0085x; 1.0085x over previous
//
#include <hip/hip_runtime.h>
#include <math.h>

#define NSEG   1024
#define DFEAT  128
#define EPS_F  1e-6f

// ps = softplus(ps_raw), with the reference's Threshold(-50) quirk:
// sp >= 50 -> ps = -50 (never triggers for N(0,1) inputs, kept for exactness)
__device__ __forceinline__ float softplus_thr(float v) {
    float sp = log1pf(__expf(v));
    return (sp >= 50.0f) ? -50.0f : sp;
}

// One block per graph/segment b. batch is SORTED, so segment b is the
// contiguous range [lower_bound(b), lower_bound(b+1)) — found by a uniform
// (scalar-unit) binary search per block. The whole pipeline is fused:
//   stream rows (float4/lane, branch-free) -> LDS reduce (16 partials)
//   -> g = s^(1/p) * n^(-q0) -> out[b] = g @ W.T + bias.
// No workspace, no memset, no atomics, one dispatch.
__global__ __launch_bounds__(512, 8)
void fused_pool_kernel(const float* __restrict__ x,
                       const int*   __restrict__ batch,
                       const float* __restrict__ ps_raw,
                       const float* __restrict__ qs_raw,
                       const float* __restrict__ W,
                       const float* __restrict__ bias,
                       float* __restrict__ out,
                       int n_nodes)
{
    const int b    = blockIdx.x;
    const int tid  = threadIdx.x;     // 0..511 (8 waves)
    const int w    = tid >> 6;        // wave 0..7
    const int lane = tid & 63;
    const int half = lane >> 5;       // half-wave: 0 -> row r, 1 -> row r+1
    const int f4   = lane & 31;       // feature quad 0..31 (features 4*f4..4*f4+3)

    // Two lower_bound searches (block-uniform -> compiled to SGPR/scalar loads;
    // ~19 L2-hit steps each, interleaved). end-start is the node count n (free).
    int lo0 = 0, hi0 = n_nodes;
    int lo1 = 0, hi1 = n_nodes;
    while (lo0 < hi0) { int m = (lo0 + hi0) >> 1; if (batch[m] < b)     lo0 = m + 1; else hi0 = m; }
    while (lo1 < hi1) { int m = (lo1 + hi1) >> 1; if (batch[m] < b + 1) lo1 = m + 1; else hi1 = m; }
    const int start = lo0, end = lo1;

    // Feature quad 4*f4..4*f4+3 sits entirely in one half of D -> p lane-constant.
    const float p = softplus_thr(ps_raw[(f4 < 16) ? 0 : 1]);

    // Branch-free streaming: half-wave h of wave w owns rows start+2w+h, stride 16.
    // Wave reads 2 adjacent rows = 1 KiB contiguous per iteration, 16 B/lane.
    const float4* __restrict__ x4 = (const float4*)x;   // row = 32 float4
    float a0 = 0.f, a1 = 0.f, a2 = 0.f, a3 = 0.f;
#pragma unroll 2
    for (int r = start + 2 * w + half; r < end; r += 16) {
        const float4 v = x4[(size_t)r * 32 + f4];
        a0 += __expf(p * __logf(fabsf(v.x) + EPS_F));   // |x|^p
        a1 += __expf(p * __logf(fabsf(v.y) + EPS_F));
        a2 += __expf(p * __logf(fabsf(v.z) + EPS_F));
        a3 += __expf(p * __logf(fabsf(v.w) + EPS_F));
    }

    // 16 partial vectors (8 waves x 2 half-waves) -> LDS, tree-sum by 128 threads.
    __shared__ float part[16][DFEAT + 4];   // +4 floats pad, keeps float4 alignment
    __shared__ float g[DFEAT];
    float4* dst = (float4*)&part[2 * w + half][4 * f4];
    *dst = make_float4(a0, a1, a2, a3);
    __syncthreads();

    if (tid < DFEAT) {
        float ssum = 0.f;
#pragma unroll
        for (int k = 0; k < 16; ++k) ssum += part[k][tid];   // contiguous -> conflict-free
        const float pf = softplus_thr(ps_raw[(tid < 64) ? 0 : 1]);
        const float q0 = tanhf(qs_raw[0]);
        const float n  = (float)(end - start);
        // g = s^(1/p) * n^(-q0)  (single exp: exp(log(s)/p - q0*log(n)))
        g[tid] = __expf(__logf(ssum) / pf - q0 * __logf(n));
    }
    __syncthreads();

    if (tid >= DFEAT) return;   // waves 2..7 done (no barriers past this point)

    // out[b][i] = dot(g, W[i][:]) + bias[i]; W is 64 KB -> L2-resident.
    const float4* __restrict__ W4 = (const float4*)(W + (size_t)tid * DFEAT);
    const float4* g4 = (const float4*)g;    // uniform address -> LDS broadcast
    float acc = bias[tid];
#pragma unroll
    for (int jj = 0; jj < DFEAT / 4; ++jj) {
        const float4 wv = W4[jj];
        const float4 gv = g4[jj];
        acc += gv.x * wv.x + gv.y * wv.y + gv.z * wv.z + gv.w * wv.w;
    }
    out[(size_t)b * DFEAT + tid] = acc;
}

extern "C" void kernel_launch(void* const* d_in, const int* in_sizes, int n_in,
                              void* d_out, int out_size, void* d_ws, size_t ws_size,
                              hipStream_t stream)
{
    const float* x      = (const float*)d_in[0];
    const int*   batch  = (const int*)  d_in[1];
    const float* ps_raw = (const float*)d_in[2];
    const float* qs_raw = (const float*)d_in[3];
    const float* W      = (const float*)d_in[4];
    const float* bias   = (const float*)d_in[5];
    float*       out    = (float*)d_out;

    const int n_nodes = in_sizes[0] / DFEAT;

    // Fully fused: no workspace, no memset, single dispatch.
    fused_pool_kernel<<<NSEG, 512, 0, stream>>>(x, batch, ps_raw, qs_raw,
                                                W, bias, out, n_nodes);
}